// Round 1
// baseline (860.876 us; speedup 1.0000x reference)
//
#include <hip/hip_runtime.h>
#include <hip/hip_fp16.h>

#define B_  32
#define L_  2048
#define U_  512
#define H_  8
#define HD_ 64

typedef __attribute__((ext_vector_type(8))) _Float16 half8;
typedef __attribute__((ext_vector_type(4))) float f32x4;

// monotonic float->uint map for atomic max (works for negatives)
__device__ __forceinline__ unsigned fmap(float x) {
    unsigned u = __float_as_uint(x);
    return (u & 0x80000000u) ? ~u : (u | 0x80000000u);
}
__device__ __forceinline__ float funmap(unsigned m) {
    unsigned bits = (m & 0x80000000u) ? (m ^ 0x80000000u) : ~m;
    return __uint_as_float(bits);
}

// ---------------------------------------------------------------------------
// Kernel 0: t (B,L,U) fp32 -> fp16 (RTZ, identical to the in-loop cvt_pkrtz
// the previous kernel applied per-use — hoisted once).
// ---------------------------------------------------------------------------
__global__ void __launch_bounds__(256) t_cvt(const float* __restrict__ t,
                                             __half* __restrict__ t16) {
    const size_t id = (size_t)blockIdx.x * 256 + threadIdx.x;  // x8 floats
    const float4 a = *(const float4*)(t + id * 8);
    const float4 b = *(const float4*)(t + id * 8 + 4);
    auto p0 = __builtin_amdgcn_cvt_pkrtz(a.x, a.y);
    auto p1 = __builtin_amdgcn_cvt_pkrtz(a.z, a.w);
    auto p2 = __builtin_amdgcn_cvt_pkrtz(b.x, b.y);
    auto p3 = __builtin_amdgcn_cvt_pkrtz(b.z, b.w);
    half8 hv;
    hv[0] = p0[0]; hv[1] = p0[1]; hv[2] = p1[0]; hv[3] = p1[1];
    hv[4] = p2[0]; hv[5] = p2[1]; hv[6] = p3[0]; hv[7] = p3[1];
    *(half8*)(t16 + id * 8) = hv;
}

// ---------------------------------------------------------------------------
// Kernel 1a: repack [Wq;Wk;Wv] (O,I,3) fp32 -> fp16 in DIRECT A-FRAGMENT order:
// Wrp2[(mblk*2+wm)][frag F][lane][8], F = ((iblk*3+kk)*2+ks)*4+mi.
// A wave loads frag F with one global_load_dwordx4 at base + F*1024 + lane*16.
// ---------------------------------------------------------------------------
__global__ void repack_w2(const float* __restrict__ Wq,
                          const float* __restrict__ Wk,
                          const float* __restrict__ Wv,
                          __half* __restrict__ Wrp2) {
    int id = blockIdx.x * 256 + threadIdx.x;       // 294,912 units of 8 halves
    int mb2  = id / 12288;                         // mblk*2+wm  (0..23)
    int rem  = id % 12288;
    int F    = rem >> 6;                           // 0..191
    int lane = rem & 63;
    int mblk = mb2 >> 1, wm = mb2 & 1;
    int mi = F & 3, ks = (F >> 2) & 1, t3 = F >> 3;
    int kk = t3 % 3, iblk = t3 / 3;
    int mat = mblk >> 2;
    const float* W = (mat == 0) ? Wq : (mat == 1) ? Wk : Wv;
    int ol = ((mblk & 3) << 7) + wm * 64 + mi * 16 + (lane & 15);  // A row (m)
    int ib = iblk * 64 + ks * 32 + (lane >> 4) * 8;                // A col (k)
    half8 hv;
#pragma unroll
    for (int j = 0; j < 8; ++j)
        hv[j] = (_Float16)W[(ol * 512 + ib + j) * 3 + kk];
    *(half8*)(Wrp2 + (size_t)id * 8) = hv;
}

// Kernel 1b: transpose Wo (O,I) -> WoT (I,O) for coalesced out_kernel reads
__global__ void wot_repack(const float* __restrict__ Wo, float* __restrict__ WoT) {
    int id = blockIdx.x * 256 + threadIdx.x;       // 262,144
    int o = id & 511, i = id >> 9;
    WoT[(size_t)i * 512 + o] = Wo[(size_t)o * 512 + i];
}

// ---------------------------------------------------------------------------
// Kernel 2: fused conv1d(K=3) GEMM, fp16 B staging:
//  - A fragments: direct global->VGPR loads per-kk (32 live regs, not 96)
//  - B tile (130 rows x 64 ch fp16): async global_load_lds DMA, double-buffered,
//    prefetched one iblk ahead; swizzle baked into SOURCE addresses (16B pieces,
//    key = (row+7)&7 -> 2-way bank aliasing = free). 33.3 KB LDS total.
//  - ONE barrier per iteration (8 total). No cvt in the inner loop.
//  - __launch_bounds__(256,4): 4 blocks/CU = 4 waves/SIMD.
// ---------------------------------------------------------------------------
__global__ void __launch_bounds__(256, 4) conv_gemm(
    const __half* __restrict__ t16,   // fp16 (B,L,U)
    const __half* __restrict__ Wrp2,
    const float* __restrict__ bq,
    const float* __restrict__ bk,
    const float* __restrict__ bv,
    __half* __restrict__ kbuf, __half* __restrict__ vbuf,
    unsigned* __restrict__ qmaxU, unsigned* __restrict__ kmaxU,
    unsigned* __restrict__ vmaxU) {
    __shared__ __align__(16) __half lB16[2][130 * 64];   // 33,280 B total

    const int tid  = threadIdx.x;
    const int lane = tid & 63;
    const int w    = tid >> 6;
    const int wm = w >> 1, wn = w & 1;
    // XCD swizzle: same-ntile's 12 mblk blocks land consecutively on ONE XCD.
    const int xcd  = blockIdx.x & 7;
    const int slot = blockIdx.x >> 3;          // 0..767
    const int ntile = xcd + 8 * (slot / 12);   // 0..511
    const int mblk  = slot % 12;
    const int bb = ntile >> 4;
    const int l0 = (ntile & 15) << 7;
    const int lane15 = lane & 15, kgrp = lane >> 4;

    const char* Abase = (const char*)Wrp2 + (size_t)(mblk * 2 + wm) * 196608;
    const __half* tB = t16 + (size_t)bb * L_ * U_;

    f32x4 acc[4][4];
#pragma unroll
    for (int a = 0; a < 4; ++a)
#pragma unroll
        for (int c = 0; c < 4; ++c) acc[a][c] = (f32x4){0.f, 0.f, 0.f, 0.f};

    // ---- B-stage: async DMA of 130 rows x 128B, swizzled source ----
    auto stageB = [&](int nb, int buf) {
        const int i0 = nb << 6;
#pragma unroll
        for (int d = 0; d < 4; ++d) {
            const int rowb = w * 32 + d * 8;               // wave-uniform
            const int row  = rowb + (lane >> 3);
            const int l    = l0 - 1 + row;
            const int p8   = lane & 7;
            const char* g = (const char*)(tB + (size_t)l * U_ + i0) + ((p8 ^ (l & 7)) << 4);
            if (l >= 0 && l < L_)
                __builtin_amdgcn_global_load_lds(
                    (const __attribute__((address_space(1))) unsigned int*)g,
                    (__attribute__((address_space(3))) unsigned int*)((char*)lB16[buf] + rowb * 128),
                    16, 0, 0);
        }
        if (w == 0 && lane < 16) {                         // rows 128,129
            const int row = 128 + (lane >> 3);
            const int l   = l0 - 1 + row;
            const int p8  = lane & 7;
            const char* g = (const char*)(tB + (size_t)l * U_ + i0) + ((p8 ^ (l & 7)) << 4);
            if (l >= 0 && l < L_)
                __builtin_amdgcn_global_load_lds(
                    (const __attribute__((address_space(1))) unsigned int*)g,
                    (__attribute__((address_space(3))) unsigned int*)((char*)lB16[buf] + 128 * 128),
                    16, 0, 0);
        }
    };

    // prezero the (at most one) conv-padding row in both buffers
    if (l0 == 0 && tid < 64) {
        lB16[0][tid] = (__half)0.f; lB16[1][tid] = (__half)0.f;
    }
    if (l0 == 1920 && tid < 64) {
        lB16[0][129 * 64 + tid] = (__half)0.f; lB16[1][129 * 64 + tid] = (__half)0.f;
    }

    stageB(0, 0);
    __syncthreads();

    for (int iblk = 0; iblk < 8; ++iblk) {
        const int cur = iblk & 1;
        const char* bbase = (const char*)lB16[cur];
#pragma unroll
        for (int kk = 0; kk < 3; ++kk) {
            // ---- A fragments for THIS kk only: 8 half8 = 32 VGPRs live ----
            half8 af[2][4];
#pragma unroll
            for (int ks = 0; ks < 2; ++ks)
#pragma unroll
                for (int mi = 0; mi < 4; ++mi)
                    af[ks][mi] = *(const half8*)(Abase +
                        ((((size_t)iblk * 3 + kk) * 2 + ks) * 4 + mi) * 1024 + lane * 16);
            // prefetch next B tile right after first A batch is in flight
            if (kk == 0 && iblk < 7) stageB(iblk + 1, cur ^ 1);
#pragma unroll
            for (int ks = 0; ks < 2; ++ks) {
                half8 bfr[4];
#pragma unroll
                for (int ni = 0; ni < 4; ++ni) {
                    const int rbuf = wn * 64 + ni * 16 + lane15 + kk;
                    const int key  = (rbuf + 7) & 7;       // = (lane15+kk+7)&7
                    const int p    = ks * 4 + kgrp;        // 16B piece 0..7
                    bfr[ni] = *(const half8*)(bbase + rbuf * 128 + ((p ^ key) << 4));
                }
#pragma unroll
                for (int mi = 0; mi < 4; ++mi)
#pragma unroll
                    for (int ni = 0; ni < 4; ++ni)
                        acc[mi][ni] = __builtin_amdgcn_mfma_f32_16x16x32_f16(
                            af[ks][mi], bfr[ni], acc[mi][ni], 0, 0, 0);
            }
        }
        __syncthreads();
    }

    // ---- epilogue ----
    const int mat = mblk >> 2;                         // 0=q 1=k 2=v
    const float* bias = (mat == 0) ? bq : (mat == 1) ? bk : bv;
    const int oBase = ((mblk & 3) << 7) + wm * 64 + kgrp * 4;
#pragma unroll
    for (int mi = 0; mi < 4; ++mi) {
#pragma unroll
        for (int r = 0; r < 4; ++r) {
            const int o = oBase + mi * 16 + r;         // channel within matrix
            const float bsv = bias[o];
            float vals[4];
            float mx = -3.0e38f;
#pragma unroll
            for (int ni = 0; ni < 4; ++ni) {
                float v = acc[mi][ni][r] + bsv;
                vals[ni] = v;
                mx = fmaxf(mx, v);
            }
#pragma unroll
            for (int d = 1; d < 16; d <<= 1) mx = fmaxf(mx, __shfl_xor(mx, d, 64));
            if (mat == 0) {
                if (lane15 == 0) atomicMax(&qmaxU[bb * U_ + o], fmap(mx));
            } else {
                __half* buf = (mat == 1) ? kbuf : vbuf;
                size_t rowbase = ((size_t)bb * U_ + o) * L_ + l0 + wn * 64;
#pragma unroll
                for (int ni = 0; ni < 4; ++ni)
                    buf[rowbase + ni * 16 + lane15] = __float2half(vals[ni]);
                unsigned* mptr = (mat == 1) ? kmaxU : vmaxU;
                if (lane15 == 0) atomicMax(&mptr[bb * U_ + o], fmap(mx));
            }
        }
    }
}

// ---------------------------------------------------------------------------
// Kernel 3: per-(b,h) attention, 1024 threads. k-pass: one aligned dword load
// + 2 shfl per thread-iter (edges scalar only at wave boundaries).
// ---------------------------------------------------------------------------
__global__ void __launch_bounds__(1024) attn_kernel(
    const __half* __restrict__ kbuf, const __half* __restrict__ vbuf,
    const unsigned* __restrict__ qmaxU, const unsigned* __restrict__ kmaxU,
    const unsigned* __restrict__ vmaxU,
    const int* __restrict__ g_mask, const int* __restrict__ t_mask,
    float* __restrict__ attout) {
    const int bh = blockIdx.x;
    const int b = bh >> 3, h = bh & 7;
    const int tid = threadIdx.x;
    const int lane = tid & 63;
    __shared__ float qs[64], kg[64], vg[64];
    __shared__ float pl[2048];
    __shared__ float red[1024];
    if (tid < 64) {
        qs[tid] = funmap(qmaxU[b * U_ + h * 64 + tid]);
        kg[tid] = funmap(kmaxU[b * U_ + h * 64 + tid]);
        vg[tid] = funmap(vmaxU[b * U_ + h * 64 + tid]);
    }
    __syncthreads();
    const float scale = 0.044194173824159216f;   // 1/sqrt(512)

    // logits for 2048 local (pooled) keys; thread owns 2 positions
    const __half* kbase = kbuf + ((size_t)b * U_ + h * 64) * L_;
    const int l0 = tid * 2;
    float acc0 = 0.f, acc1 = 0.f;
    for (int o = 0; o < 64; ++o) {
        const __half* row = kbase + (size_t)o * L_;
        const __half2 hv = *(const __half2*)(row + l0);
        float f1 = __half2float(hv.x), f2 = __half2float(hv.y);
        float fL = __shfl_up(f2, 1, 64);
        float fR = __shfl_down(f1, 1, 64);
        if (lane == 0)  fL = (l0 == 0) ? -3.0e38f : __half2float(row[l0 - 1]);
        if (lane == 63) fR = (l0 + 2 >= L_) ? -3.0e38f : __half2float(row[l0 + 2]);
        const float qw = qs[o];
        acc0 += qw * fmaxf(fL, fmaxf(f1, f2));
        acc1 += qw * fmaxf(f1, fmaxf(f2, fR));
    }
    float lmax = -3.0e38f;
    {
        int tm0 = t_mask[b * L_ + l0], tm1 = t_mask[b * L_ + l0 + 1];
        float lg0 = (tm0 == 0) ? -INFINITY : acc0 * scale;
        float lg1 = (tm1 == 0) ? -INFINITY : acc1 * scale;
        pl[l0] = lg0; pl[l0 + 1] = lg1;
        lmax = fmaxf(lg0, lg1);
    }
    // global-key logit (redundantly on all threads; cheap)
    float ag = 0.f;
    for (int d = 0; d < 64; ++d) ag += qs[d] * kg[d];
    const int gm = g_mask[b];
    float lgg = gm ? ag * scale : -INFINITY;
    // block max
    red[tid] = lmax; __syncthreads();
    for (int s = 512; s > 0; s >>= 1) {
        if (tid < s) red[tid] = fmaxf(red[tid], red[tid + s]);
        __syncthreads();
    }
    float mx = fmaxf(red[0], lgg);
    __syncthreads();
    // exponentials + denominator
    {
        float lg0 = pl[l0], lg1 = pl[l0 + 1];
        float e0 = (lg0 <= -3.0e38f) ? 0.f : __expf(lg0 - mx);
        float e1 = (lg1 <= -3.0e38f) ? 0.f : __expf(lg1 - mx);
        pl[l0] = e0; pl[l0 + 1] = e1;
        red[tid] = e0 + e1;
    }
    __syncthreads();
    for (int s = 512; s > 0; s >>= 1) {
        if (tid < s) red[tid] += red[tid + s];
        __syncthreads();
    }
    float eg = gm ? __expf(lgg - mx) : 0.f;
    float den = red[0] + eg;
    if (!(den > 0.f)) den = 1.f;
    __syncthreads();
    // weighted sum of pooled values: thread = (o = tid/16, 16 chunks of 128 l's)
    const int o = tid >> 4;
    const int ch = tid & 15;
    const __half* vrow = vbuf + ((size_t)b * U_ + h * 64 + o) * L_;
    float s = 0.f;
    for (int lb = ch * 128; lb < ch * 128 + 128; lb += 8) {
        union { uint4 u; __half hh[8]; } pk;
        pk.u = *(const uint4*)(vrow + lb);
        float f[10];
#pragma unroll
        for (int j = 0; j < 8; ++j) f[j + 1] = __half2float(pk.hh[j]);
        f[0] = (lb == 0) ? -3.0e38f : __half2float(vrow[lb - 1]);
        f[9] = (lb + 8 >= L_) ? -3.0e38f : __half2float(vrow[lb + 8]);
#pragma unroll
        for (int j = 0; j < 8; ++j)
            s += pl[lb + j] * fmaxf(f[j], fmaxf(f[j + 1], f[j + 2]));
    }
    red[tid] = s; __syncthreads();
    if (ch == 0) {
        float tot = 0.f;
#pragma unroll
        for (int q2 = 0; q2 < 16; ++q2) tot += red[(o << 4) + q2];
        float val = (eg * vg[o] + tot) / den;
        val *= (float)gm;
        attout[(size_t)b * U_ + h * 64 + o] = val;
    }
}

// ---------------------------------------------------------------------------
// Kernel 4: head mix (H x H) + output projection via WoT (coalesced)
// ---------------------------------------------------------------------------
__global__ void __launch_bounds__(512) out_kernel(
    const float* __restrict__ attout,
    const float* __restrict__ Wh, const float* __restrict__ bh,
    const float* __restrict__ WoT, const float* __restrict__ bo,
    float* __restrict__ out) {
    const int b = blockIdx.x;
    const int tid = threadIdx.x;
    __shared__ float tmp[512];
    const int oh = tid >> 6, d = tid & 63;
    float s = bh[oh];
#pragma unroll
    for (int i = 0; i < 8; ++i)
        s += Wh[oh * 8 + i] * attout[b * U_ + i * 64 + d];
    tmp[oh * 64 + d] = s;          // u = h*64 + d
    __syncthreads();
    float s2 = bo[tid];
    for (int i = 0; i < 512; ++i) s2 += WoT[i * 512 + tid] * tmp[i];
    out[b * U_ + tid] = s2;
}

// ---------------------------------------------------------------------------
extern "C" void kernel_launch(void* const* d_in, const int* in_sizes, int n_in,
                              void* d_out, int out_size, void* d_ws, size_t ws_size,
                              hipStream_t stream) {
    const float* t  = (const float*)d_in[0];
    // d_in[1] = g : unused by the reference
    const int* g_mask = (const int*)d_in[2];
    const int* t_mask = (const int*)d_in[3];
    const float* Wq = (const float*)d_in[4];
    const float* bq = (const float*)d_in[5];
    const float* Wk = (const float*)d_in[6];
    const float* bk = (const float*)d_in[7];
    const float* Wv = (const float*)d_in[8];
    const float* bv = (const float*)d_in[9];
    const float* Wh = (const float*)d_in[10];
    const float* bh = (const float*)d_in[11];
    const float* Wo = (const float*)d_in[12];
    const float* bo = (const float*)d_in[13];

    char* ws = (char*)d_ws;
    __half* Wrp2 = (__half*)ws;                                      // 4,718,592 B
    float* WoT   = (float*)(ws + 4718592);                           // 1,048,576 B
    __half* t16  = (__half*)(ws + 5767168);                          // 67,108,864 B
    __half* kbuf = (__half*)(ws + 5767168 + 67108864);               // 67,108,864 B
    __half* vbuf = (__half*)(ws + 5767168 + 2 * 67108864);           // 67,108,864 B
    unsigned* qmaxU = (unsigned*)(ws + 5767168 + 3 * 67108864);
    unsigned* kmaxU = qmaxU + 16384;
    unsigned* vmaxU = kmaxU + 16384;
    float* attout = (float*)(vmaxU + 16384);

    (void)hipMemsetAsync(qmaxU, 0, 3 * 16384 * sizeof(unsigned), stream);
    t_cvt<<<16384, 256, 0, stream>>>(t, t16);
    repack_w2<<<1152, 256, 0, stream>>>(Wq, Wk, Wv, Wrp2);
    wot_repack<<<1024, 256, 0, stream>>>(Wo, WoT);
    conv_gemm<<<6144, 256, 0, stream>>>(t16, Wrp2, bq, bk, bv, kbuf, vbuf,
                                        qmaxU, kmaxU, vmaxU);
    attn_kernel<<<256, 1024, 0, stream>>>(kbuf, vbuf, qmaxU, kmaxU, vmaxU,
                                          g_mask, t_mask, attout);
    out_kernel<<<32, 512, 0, stream>>>(attout, Wh, bh, WoT, bo, (float*)d_out);
}

// Round 2
// 688.663 us; speedup vs baseline: 1.2501x; 1.2501x over previous
//
#include <hip/hip_runtime.h>
#include <hip/hip_fp16.h>

#define B_  32
#define L_  2048
#define U_  512
#define H_  8
#define HD_ 64

typedef __attribute__((ext_vector_type(8))) _Float16 half8;
typedef __attribute__((ext_vector_type(4))) float f32x4;

// monotonic float->uint map for atomic max (works for negatives)
__device__ __forceinline__ unsigned fmap(float x) {
    unsigned u = __float_as_uint(x);
    return (u & 0x80000000u) ? ~u : (u | 0x80000000u);
}
__device__ __forceinline__ float funmap(unsigned m) {
    unsigned bits = (m & 0x80000000u) ? (m ^ 0x80000000u) : ~m;
    return __uint_as_float(bits);
}

// ---------------------------------------------------------------------------
// Kernel 0: t (B,L,U) fp32 -> fp16 (RTZ, hoisted from the GEMM inner loop).
// ---------------------------------------------------------------------------
__global__ void __launch_bounds__(256) t_cvt(const float* __restrict__ t,
                                             __half* __restrict__ t16) {
    const size_t id = (size_t)blockIdx.x * 256 + threadIdx.x;  // x8 floats
    const float4 a = *(const float4*)(t + id * 8);
    const float4 b = *(const float4*)(t + id * 8 + 4);
    auto p0 = __builtin_amdgcn_cvt_pkrtz(a.x, a.y);
    auto p1 = __builtin_amdgcn_cvt_pkrtz(a.z, a.w);
    auto p2 = __builtin_amdgcn_cvt_pkrtz(b.x, b.y);
    auto p3 = __builtin_amdgcn_cvt_pkrtz(b.z, b.w);
    half8 hv;
    hv[0] = p0[0]; hv[1] = p0[1]; hv[2] = p1[0]; hv[3] = p1[1];
    hv[4] = p2[0]; hv[5] = p2[1]; hv[6] = p3[0]; hv[7] = p3[1];
    *(half8*)(t16 + id * 8) = hv;
}

// ---------------------------------------------------------------------------
// Kernel 1a: repack [Wq;Wk;Wv] (O,I,3) fp32 -> fp16 in DIRECT A-FRAGMENT order:
// Wrp2[(mblk*2+wm)][frag F][lane][8], F = ((iblk*3+kk)*2+ks)*4+mi.
// A wave loads frag F with one global_load_dwordx4 at base + F*1024 + lane*16.
// ---------------------------------------------------------------------------
__global__ void repack_w2(const float* __restrict__ Wq,
                          const float* __restrict__ Wk,
                          const float* __restrict__ Wv,
                          __half* __restrict__ Wrp2) {
    int id = blockIdx.x * 256 + threadIdx.x;       // 294,912 units of 8 halves
    int mb2  = id / 12288;                         // mblk*2+wm  (0..23)
    int rem  = id % 12288;
    int F    = rem >> 6;                           // 0..191
    int lane = rem & 63;
    int mblk = mb2 >> 1, wm = mb2 & 1;
    int mi = F & 3, ks = (F >> 2) & 1, t3 = F >> 3;
    int kk = t3 % 3, iblk = t3 / 3;
    int mat = mblk >> 2;
    const float* W = (mat == 0) ? Wq : (mat == 1) ? Wk : Wv;
    int ol = ((mblk & 3) << 7) + wm * 64 + mi * 16 + (lane & 15);  // A row (m)
    int ib = iblk * 64 + ks * 32 + (lane >> 4) * 8;                // A col (k)
    half8 hv;
#pragma unroll
    for (int j = 0; j < 8; ++j)
        hv[j] = (_Float16)W[(ol * 512 + ib + j) * 3 + kk];
    *(half8*)(Wrp2 + (size_t)id * 8) = hv;
}

// Kernel 1b: transpose Wo (O,I) -> WoT (I,O) for coalesced out_kernel reads
__global__ void wot_repack(const float* __restrict__ Wo, float* __restrict__ WoT) {
    int id = blockIdx.x * 256 + threadIdx.x;       // 262,144
    int o = id & 511, i = id >> 9;
    WoT[(size_t)i * 512 + o] = Wo[(size_t)o * 512 + i];
}

// ---------------------------------------------------------------------------
// Kernel 2: fused conv1d(K=3) GEMM, fp16 B staging:
//  - A fragments: direct global->VGPR loads per-(kk,ks) (16 live regs)
//  - B tile (130 rows x 64 ch fp16): async global_load_lds DMA, double-buffered,
//    prefetched one iblk ahead; swizzle baked into SOURCE addresses (16B pieces,
//    key = (row+7)&7 -> conflict-free ds_read_b128). 33.3 KB LDS total.
//  - ONE barrier per iteration (8 total). No cvt in the inner loop.
//  - __launch_bounds__(256,3): budget ~170 VGPR -> NO SPILL (round-1 lesson:
//    (256,4) forced a 64-VGPR clamp and 700 MB of scratch traffic).
// ---------------------------------------------------------------------------
__global__ void __launch_bounds__(256, 3) conv_gemm(
    const __half* __restrict__ t16,   // fp16 (B,L,U)
    const __half* __restrict__ Wrp2,
    const float* __restrict__ bq,
    const float* __restrict__ bk,
    const float* __restrict__ bv,
    __half* __restrict__ kbuf, __half* __restrict__ vbuf,
    unsigned* __restrict__ qmaxU, unsigned* __restrict__ kmaxU,
    unsigned* __restrict__ vmaxU) {
    __shared__ __align__(16) __half lB16[2][130 * 64];   // 33,280 B total

    const int tid  = threadIdx.x;
    const int lane = tid & 63;
    const int w    = tid >> 6;
    const int wm = w >> 1, wn = w & 1;
    // XCD swizzle: same-ntile's 12 mblk blocks land consecutively on ONE XCD.
    const int xcd  = blockIdx.x & 7;
    const int slot = blockIdx.x >> 3;          // 0..767
    const int ntile = xcd + 8 * (slot / 12);   // 0..511
    const int mblk  = slot % 12;
    const int bb = ntile >> 4;
    const int l0 = (ntile & 15) << 7;
    const int lane15 = lane & 15, kgrp = lane >> 4;

    const char* Abase = (const char*)Wrp2 + (size_t)(mblk * 2 + wm) * 196608;
    const __half* tB = t16 + (size_t)bb * L_ * U_;

    f32x4 acc[4][4];
#pragma unroll
    for (int a = 0; a < 4; ++a)
#pragma unroll
        for (int c = 0; c < 4; ++c) acc[a][c] = (f32x4){0.f, 0.f, 0.f, 0.f};

    // ---- B-stage: async DMA of 130 rows x 128B, swizzled source ----
    auto stageB = [&](int nb, int buf) {
        const int i0 = nb << 6;
#pragma unroll
        for (int d = 0; d < 4; ++d) {
            const int rowb = w * 32 + d * 8;               // wave-uniform
            const int row  = rowb + (lane >> 3);
            const int l    = l0 - 1 + row;
            const int p8   = lane & 7;
            const char* g = (const char*)(tB + (size_t)l * U_ + i0) + ((p8 ^ (l & 7)) << 4);
            if (l >= 0 && l < L_)
                __builtin_amdgcn_global_load_lds(
                    (const __attribute__((address_space(1))) unsigned int*)g,
                    (__attribute__((address_space(3))) unsigned int*)((char*)lB16[buf] + rowb * 128),
                    16, 0, 0);
        }
        if (w == 0 && lane < 16) {                         // rows 128,129
            const int row = 128 + (lane >> 3);
            const int l   = l0 - 1 + row;
            const int p8  = lane & 7;
            const char* g = (const char*)(tB + (size_t)l * U_ + i0) + ((p8 ^ (l & 7)) << 4);
            if (l >= 0 && l < L_)
                __builtin_amdgcn_global_load_lds(
                    (const __attribute__((address_space(1))) unsigned int*)g,
                    (__attribute__((address_space(3))) unsigned int*)((char*)lB16[buf] + 128 * 128),
                    16, 0, 0);
        }
    };

    // prezero the (at most one) conv-padding row in both buffers
    if (l0 == 0 && tid < 64) {
        lB16[0][tid] = (__half)0.f; lB16[1][tid] = (__half)0.f;
    }
    if (l0 == 1920 && tid < 64) {
        lB16[0][129 * 64 + tid] = (__half)0.f; lB16[1][129 * 64 + tid] = (__half)0.f;
    }

    stageB(0, 0);
    __syncthreads();

    for (int iblk = 0; iblk < 8; ++iblk) {
        const int cur = iblk & 1;
        const char* bbase = (const char*)lB16[cur];
#pragma unroll
        for (int kk = 0; kk < 3; ++kk) {
#pragma unroll
            for (int ks = 0; ks < 2; ++ks) {
                // ---- A fragments for THIS (kk,ks): 4 half8 = 16 VGPRs live ----
                half8 af[4];
#pragma unroll
                for (int mi = 0; mi < 4; ++mi)
                    af[mi] = *(const half8*)(Abase +
                        ((((size_t)iblk * 3 + kk) * 2 + ks) * 4 + mi) * 1024 + lane * 16);
                // prefetch next B tile early in the iteration
                if (kk == 0 && ks == 0 && iblk < 7) stageB(iblk + 1, cur ^ 1);
                half8 bfr[4];
#pragma unroll
                for (int ni = 0; ni < 4; ++ni) {
                    const int rbuf = wn * 64 + ni * 16 + lane15 + kk;
                    const int key  = (rbuf + 7) & 7;       // = (lane15+kk+7)&7
                    const int p    = ks * 4 + kgrp;        // 16B piece 0..7
                    bfr[ni] = *(const half8*)(bbase + rbuf * 128 + ((p ^ key) << 4));
                }
#pragma unroll
                for (int mi = 0; mi < 4; ++mi)
#pragma unroll
                    for (int ni = 0; ni < 4; ++ni)
                        acc[mi][ni] = __builtin_amdgcn_mfma_f32_16x16x32_f16(
                            af[mi], bfr[ni], acc[mi][ni], 0, 0, 0);
            }
        }
        __syncthreads();
    }

    // ---- epilogue ----
    const int mat = mblk >> 2;                         // 0=q 1=k 2=v
    const float* bias = (mat == 0) ? bq : (mat == 1) ? bk : bv;
    const int oBase = ((mblk & 3) << 7) + wm * 64 + kgrp * 4;
#pragma unroll
    for (int mi = 0; mi < 4; ++mi) {
#pragma unroll
        for (int r = 0; r < 4; ++r) {
            const int o = oBase + mi * 16 + r;         // channel within matrix
            const float bsv = bias[o];
            float vals[4];
            float mx = -3.0e38f;
#pragma unroll
            for (int ni = 0; ni < 4; ++ni) {
                float v = acc[mi][ni][r] + bsv;
                vals[ni] = v;
                mx = fmaxf(mx, v);
            }
#pragma unroll
            for (int d = 1; d < 16; d <<= 1) mx = fmaxf(mx, __shfl_xor(mx, d, 64));
            if (mat == 0) {
                if (lane15 == 0) atomicMax(&qmaxU[bb * U_ + o], fmap(mx));
            } else {
                __half* buf = (mat == 1) ? kbuf : vbuf;
                size_t rowbase = ((size_t)bb * U_ + o) * L_ + l0 + wn * 64;
#pragma unroll
                for (int ni = 0; ni < 4; ++ni)
                    buf[rowbase + ni * 16 + lane15] = __float2half(vals[ni]);
                unsigned* mptr = (mat == 1) ? kmaxU : vmaxU;
                if (lane15 == 0) atomicMax(&mptr[bb * U_ + o], fmap(mx));
            }
        }
    }
}

// ---------------------------------------------------------------------------
// Kernel 3: per-(b,h) attention, 1024 threads. k-pass: one aligned dword load
// + 2 shfl per thread-iter (edges scalar only at wave boundaries).
// ---------------------------------------------------------------------------
__global__ void __launch_bounds__(1024) attn_kernel(
    const __half* __restrict__ kbuf, const __half* __restrict__ vbuf,
    const unsigned* __restrict__ qmaxU, const unsigned* __restrict__ kmaxU,
    const unsigned* __restrict__ vmaxU,
    const int* __restrict__ g_mask, const int* __restrict__ t_mask,
    float* __restrict__ attout) {
    const int bh = blockIdx.x;
    const int b = bh >> 3, h = bh & 7;
    const int tid = threadIdx.x;
    const int lane = tid & 63;
    __shared__ float qs[64], kg[64], vg[64];
    __shared__ float pl[2048];
    __shared__ float red[1024];
    if (tid < 64) {
        qs[tid] = funmap(qmaxU[b * U_ + h * 64 + tid]);
        kg[tid] = funmap(kmaxU[b * U_ + h * 64 + tid]);
        vg[tid] = funmap(vmaxU[b * U_ + h * 64 + tid]);
    }
    __syncthreads();
    const float scale = 0.044194173824159216f;   // 1/sqrt(512)

    // logits for 2048 local (pooled) keys; thread owns 2 positions
    const __half* kbase = kbuf + ((size_t)b * U_ + h * 64) * L_;
    const int l0 = tid * 2;
    float acc0 = 0.f, acc1 = 0.f;
    for (int o = 0; o < 64; ++o) {
        const __half* row = kbase + (size_t)o * L_;
        const __half2 hv = *(const __half2*)(row + l0);
        float f1 = __half2float(hv.x), f2 = __half2float(hv.y);
        float fL = __shfl_up(f2, 1, 64);
        float fR = __shfl_down(f1, 1, 64);
        if (lane == 0)  fL = (l0 == 0) ? -3.0e38f : __half2float(row[l0 - 1]);
        if (lane == 63) fR = (l0 + 2 >= L_) ? -3.0e38f : __half2float(row[l0 + 2]);
        const float qw = qs[o];
        acc0 += qw * fmaxf(fL, fmaxf(f1, f2));
        acc1 += qw * fmaxf(f1, fmaxf(f2, fR));
    }
    float lmax = -3.0e38f;
    {
        int tm0 = t_mask[b * L_ + l0], tm1 = t_mask[b * L_ + l0 + 1];
        float lg0 = (tm0 == 0) ? -INFINITY : acc0 * scale;
        float lg1 = (tm1 == 0) ? -INFINITY : acc1 * scale;
        pl[l0] = lg0; pl[l0 + 1] = lg1;
        lmax = fmaxf(lg0, lg1);
    }
    // global-key logit (redundantly on all threads; cheap)
    float ag = 0.f;
    for (int d = 0; d < 64; ++d) ag += qs[d] * kg[d];
    const int gm = g_mask[b];
    float lgg = gm ? ag * scale : -INFINITY;
    // block max
    red[tid] = lmax; __syncthreads();
    for (int s = 512; s > 0; s >>= 1) {
        if (tid < s) red[tid] = fmaxf(red[tid], red[tid + s]);
        __syncthreads();
    }
    float mx = fmaxf(red[0], lgg);
    __syncthreads();
    // exponentials + denominator
    {
        float lg0 = pl[l0], lg1 = pl[l0 + 1];
        float e0 = (lg0 <= -3.0e38f) ? 0.f : __expf(lg0 - mx);
        float e1 = (lg1 <= -3.0e38f) ? 0.f : __expf(lg1 - mx);
        pl[l0] = e0; pl[l0 + 1] = e1;
        red[tid] = e0 + e1;
    }
    __syncthreads();
    for (int s = 512; s > 0; s >>= 1) {
        if (tid < s) red[tid] += red[tid + s];
        __syncthreads();
    }
    float eg = gm ? __expf(lgg - mx) : 0.f;
    float den = red[0] + eg;
    if (!(den > 0.f)) den = 1.f;
    __syncthreads();
    // weighted sum of pooled values: thread = (o = tid/16, 16 chunks of 128 l's)
    const int o = tid >> 4;
    const int ch = tid & 15;
    const __half* vrow = vbuf + ((size_t)b * U_ + h * 64 + o) * L_;
    float s = 0.f;
    for (int lb = ch * 128; lb < ch * 128 + 128; lb += 8) {
        union { uint4 u; __half hh[8]; } pk;
        pk.u = *(const uint4*)(vrow + lb);
        float f[10];
#pragma unroll
        for (int j = 0; j < 8; ++j) f[j + 1] = __half2float(pk.hh[j]);
        f[0] = (lb == 0) ? -3.0e38f : __half2float(vrow[lb - 1]);
        f[9] = (lb + 8 >= L_) ? -3.0e38f : __half2float(vrow[lb + 8]);
#pragma unroll
        for (int j = 0; j < 8; ++j)
            s += pl[lb + j] * fmaxf(f[j], fmaxf(f[j + 1], f[j + 2]));
    }
    red[tid] = s; __syncthreads();
    if (ch == 0) {
        float tot = 0.f;
#pragma unroll
        for (int q2 = 0; q2 < 16; ++q2) tot += red[(o << 4) + q2];
        float val = (eg * vg[o] + tot) / den;
        val *= (float)gm;
        attout[(size_t)b * U_ + h * 64 + o] = val;
    }
}

// ---------------------------------------------------------------------------
// Kernel 4: head mix (H x H) + output projection via WoT (coalesced)
// ---------------------------------------------------------------------------
__global__ void __launch_bounds__(512) out_kernel(
    const float* __restrict__ attout,
    const float* __restrict__ Wh, const float* __restrict__ bh,
    const float* __restrict__ WoT, const float* __restrict__ bo,
    float* __restrict__ out) {
    const int b = blockIdx.x;
    const int tid = threadIdx.x;
    __shared__ float tmp[512];
    const int oh = tid >> 6, d = tid & 63;
    float s = bh[oh];
#pragma unroll
    for (int i = 0; i < 8; ++i)
        s += Wh[oh * 8 + i] * attout[b * U_ + i * 64 + d];
    tmp[oh * 64 + d] = s;          // u = h*64 + d
    __syncthreads();
    float s2 = bo[tid];
    for (int i = 0; i < 512; ++i) s2 += WoT[i * 512 + tid] * tmp[i];
    out[b * U_ + tid] = s2;
}

// ---------------------------------------------------------------------------
extern "C" void kernel_launch(void* const* d_in, const int* in_sizes, int n_in,
                              void* d_out, int out_size, void* d_ws, size_t ws_size,
                              hipStream_t stream) {
    const float* t  = (const float*)d_in[0];
    // d_in[1] = g : unused by the reference
    const int* g_mask = (const int*)d_in[2];
    const int* t_mask = (const int*)d_in[3];
    const float* Wq = (const float*)d_in[4];
    const float* bq = (const float*)d_in[5];
    const float* Wk = (const float*)d_in[6];
    const float* bk = (const float*)d_in[7];
    const float* Wv = (const float*)d_in[8];
    const float* bv = (const float*)d_in[9];
    const float* Wh = (const float*)d_in[10];
    const float* bh = (const float*)d_in[11];
    const float* Wo = (const float*)d_in[12];
    const float* bo = (const float*)d_in[13];

    char* ws = (char*)d_ws;
    __half* Wrp2 = (__half*)ws;                                      // 4,718,592 B
    float* WoT   = (float*)(ws + 4718592);                           // 1,048,576 B
    __half* t16  = (__half*)(ws + 5767168);                          // 67,108,864 B
    __half* kbuf = (__half*)(ws + 5767168 + 67108864);               // 67,108,864 B
    __half* vbuf = (__half*)(ws + 5767168 + 2 * 67108864);           // 67,108,864 B
    unsigned* qmaxU = (unsigned*)(ws + 5767168 + 3 * 67108864);
    unsigned* kmaxU = qmaxU + 16384;
    unsigned* vmaxU = kmaxU + 16384;
    float* attout = (float*)(vmaxU + 16384);

    (void)hipMemsetAsync(qmaxU, 0, 3 * 16384 * sizeof(unsigned), stream);
    t_cvt<<<16384, 256, 0, stream>>>(t, t16);
    repack_w2<<<1152, 256, 0, stream>>>(Wq, Wk, Wv, Wrp2);
    wot_repack<<<1024, 256, 0, stream>>>(Wo, WoT);
    conv_gemm<<<6144, 256, 0, stream>>>(t16, Wrp2, bq, bk, bv, kbuf, vbuf,
                                        qmaxU, kmaxU, vmaxU);
    attn_kernel<<<256, 1024, 0, stream>>>(kbuf, vbuf, qmaxU, kmaxU, vmaxU,
                                          g_mask, t_mask, attout);
    out_kernel<<<32, 512, 0, stream>>>(attout, Wh, bh, WoT, bo, (float*)d_out);
}

// Round 3
// 651.262 us; speedup vs baseline: 1.3219x; 1.0574x over previous
//
#include <hip/hip_runtime.h>
#include <hip/hip_fp16.h>

#define B_  32
#define L_  2048
#define U_  512
#define H_  8
#define HD_ 64

typedef __attribute__((ext_vector_type(8))) _Float16 half8;
typedef __attribute__((ext_vector_type(4))) float f32x4;

// monotonic float->uint map for atomic max (works for negatives)
__device__ __forceinline__ unsigned fmap(float x) {
    unsigned u = __float_as_uint(x);
    return (u & 0x80000000u) ? ~u : (u | 0x80000000u);
}
__device__ __forceinline__ float funmap(unsigned m) {
    unsigned bits = (m & 0x80000000u) ? (m ^ 0x80000000u) : ~m;
    return __uint_as_float(bits);
}

// ---------------------------------------------------------------------------
// Kernel 0: t (B,L,U) fp32 -> fp16 (RTZ, hoisted from the GEMM inner loop).
// ---------------------------------------------------------------------------
__global__ void __launch_bounds__(256) t_cvt(const float* __restrict__ t,
                                             __half* __restrict__ t16) {
    const size_t id = (size_t)blockIdx.x * 256 + threadIdx.x;  // x8 floats
    const float4 a = *(const float4*)(t + id * 8);
    const float4 b = *(const float4*)(t + id * 8 + 4);
    auto p0 = __builtin_amdgcn_cvt_pkrtz(a.x, a.y);
    auto p1 = __builtin_amdgcn_cvt_pkrtz(a.z, a.w);
    auto p2 = __builtin_amdgcn_cvt_pkrtz(b.x, b.y);
    auto p3 = __builtin_amdgcn_cvt_pkrtz(b.z, b.w);
    half8 hv;
    hv[0] = p0[0]; hv[1] = p0[1]; hv[2] = p1[0]; hv[3] = p1[1];
    hv[4] = p2[0]; hv[5] = p2[1]; hv[6] = p3[0]; hv[7] = p3[1];
    *(half8*)(t16 + id * 8) = hv;
}

// ---------------------------------------------------------------------------
// Kernel 1a: repack [Wq;Wk;Wv] (O,I,3) fp32 -> fp16 in DIRECT A-FRAGMENT order:
// Wrp2[(mblk*2+wm)][frag F][lane][8], F = ((iblk*3+kk)*2+ks)*4+mi.
// A wave loads frag F with one global_load_dwordx4 at base + F*1024 + lane*16.
// ---------------------------------------------------------------------------
__global__ void repack_w2(const float* __restrict__ Wq,
                          const float* __restrict__ Wk,
                          const float* __restrict__ Wv,
                          __half* __restrict__ Wrp2) {
    int id = blockIdx.x * 256 + threadIdx.x;       // 294,912 units of 8 halves
    int mb2  = id / 12288;                         // mblk*2+wm  (0..23)
    int rem  = id % 12288;
    int F    = rem >> 6;                           // 0..191
    int lane = rem & 63;
    int mblk = mb2 >> 1, wm = mb2 & 1;
    int mi = F & 3, ks = (F >> 2) & 1, t3 = F >> 3;
    int kk = t3 % 3, iblk = t3 / 3;
    int mat = mblk >> 2;
    const float* W = (mat == 0) ? Wq : (mat == 1) ? Wk : Wv;
    int ol = ((mblk & 3) << 7) + wm * 64 + mi * 16 + (lane & 15);  // A row (m)
    int ib = iblk * 64 + ks * 32 + (lane >> 4) * 8;                // A col (k)
    half8 hv;
#pragma unroll
    for (int j = 0; j < 8; ++j)
        hv[j] = (_Float16)W[(ol * 512 + ib + j) * 3 + kk];
    *(half8*)(Wrp2 + (size_t)id * 8) = hv;
}

// Kernel 1b: transpose Wo (O,I) -> WoT (I,O) for coalesced out_kernel reads
__global__ void wot_repack(const float* __restrict__ Wo, float* __restrict__ WoT) {
    int id = blockIdx.x * 256 + threadIdx.x;       // 262,144
    int o = id & 511, i = id >> 9;
    WoT[(size_t)i * 512 + o] = Wo[(size_t)o * 512 + i];
}

// ---------------------------------------------------------------------------
// Kernel 2: fused conv1d(K=3) GEMM, fp16 B staging, 1-subphase SW pipeline:
//  - 48 subphases of {4 A global loads, 4 B ds_read_b128, 16 MFMA}; the loads
//    for subphase s+1 are issued BEFORE the MFMAs of subphase s (ping-pong
//    register buffers, static indexing). At s==5 the next iblk's A batch is
//    prefetched (no barrier dependency). MFMA (~310 SIMD-cyc) covers L2
//    latency (~300 cyc).
//  - B tile (130 rows x 64 ch fp16): async global_load_lds DMA, double-buffered,
//    swizzle baked into SOURCE addresses; conflict-free ds_read_b128.
//  - __launch_bounds__(256,3): ~170-reg budget, no spill (r1 lesson: (256,4)
//    clamps to 64 and spills 700 MB).
// ---------------------------------------------------------------------------
__global__ void __launch_bounds__(256, 3) conv_gemm(
    const __half* __restrict__ t16,   // fp16 (B,L,U)
    const __half* __restrict__ Wrp2,
    const float* __restrict__ bq,
    const float* __restrict__ bk,
    const float* __restrict__ bv,
    __half* __restrict__ kbuf, __half* __restrict__ vbuf,
    unsigned* __restrict__ qmaxU, unsigned* __restrict__ kmaxU,
    unsigned* __restrict__ vmaxU) {
    __shared__ __align__(16) __half lB16[2][130 * 64];   // 33,280 B total

    const int tid  = threadIdx.x;
    const int lane = tid & 63;
    const int w    = tid >> 6;
    const int wm = w >> 1, wn = w & 1;
    // XCD swizzle: same-ntile's 12 mblk blocks land consecutively on ONE XCD.
    const int xcd  = blockIdx.x & 7;
    const int slot = blockIdx.x >> 3;          // 0..767
    const int ntile = xcd + 8 * (slot / 12);   // 0..511
    const int mblk  = slot % 12;
    const int bb = ntile >> 4;
    const int l0 = (ntile & 15) << 7;
    const int lane15 = lane & 15, kgrp = lane >> 4;

    const char* Abase = (const char*)Wrp2 + (size_t)(mblk * 2 + wm) * 196608;
    const __half* tB = t16 + (size_t)bb * L_ * U_;

    f32x4 acc[4][4];
#pragma unroll
    for (int a = 0; a < 4; ++a)
#pragma unroll
        for (int c = 0; c < 4; ++c) acc[a][c] = (f32x4){0.f, 0.f, 0.f, 0.f};

    // ---- B-stage: async DMA of 130 rows x 128B, swizzled source ----
    auto stageB = [&](int nb, int buf) {
        const int i0 = nb << 6;
#pragma unroll
        for (int d = 0; d < 4; ++d) {
            const int rowb = w * 32 + d * 8;               // wave-uniform
            const int row  = rowb + (lane >> 3);
            const int l    = l0 - 1 + row;
            const int p8   = lane & 7;
            const char* g = (const char*)(tB + (size_t)l * U_ + i0) + ((p8 ^ (l & 7)) << 4);
            if (l >= 0 && l < L_)
                __builtin_amdgcn_global_load_lds(
                    (const __attribute__((address_space(1))) unsigned int*)g,
                    (__attribute__((address_space(3))) unsigned int*)((char*)lB16[buf] + rowb * 128),
                    16, 0, 0);
        }
        if (w == 0 && lane < 16) {                         // rows 128,129
            const int row = 128 + (lane >> 3);
            const int l   = l0 - 1 + row;
            const int p8  = lane & 7;
            const char* g = (const char*)(tB + (size_t)l * U_ + i0) + ((p8 ^ (l & 7)) << 4);
            if (l >= 0 && l < L_)
                __builtin_amdgcn_global_load_lds(
                    (const __attribute__((address_space(1))) unsigned int*)g,
                    (__attribute__((address_space(3))) unsigned int*)((char*)lB16[buf] + 128 * 128),
                    16, 0, 0);
        }
    };

    auto loadA = [&](int ib, int kk, int ks, half8* dst) {
#pragma unroll
        for (int mi = 0; mi < 4; ++mi)
            dst[mi] = *(const half8*)(Abase +
                ((((size_t)ib * 3 + kk) * 2 + ks) * 4 + mi) * 1024 + lane * 16);
    };
    auto loadB = [&](const char* bbase, int kk, int ks, half8* dst) {
#pragma unroll
        for (int ni = 0; ni < 4; ++ni) {
            const int rbuf = wn * 64 + ni * 16 + lane15 + kk;
            const int key  = (rbuf + 7) & 7;       // = (lane15+kk+7)&7
            const int p    = ks * 4 + kgrp;        // 16B piece 0..7
            dst[ni] = *(const half8*)(bbase + rbuf * 128 + ((p ^ key) << 4));
        }
    };

    // prezero the (at most one) conv-padding row in both buffers
    if (l0 == 0 && tid < 64) {
        lB16[0][tid] = (__half)0.f; lB16[1][tid] = (__half)0.f;
    }
    if (l0 == 1920 && tid < 64) {
        lB16[0][129 * 64 + tid] = (__half)0.f; lB16[1][129 * 64 + tid] = (__half)0.f;
    }

    stageB(0, 0);
    half8 afA[4], afB[4], bfA[4], bfB[4];
    loadA(0, 0, 0, afA);                     // s=0 A batch: no LDS dependency
    __syncthreads();

    for (int iblk = 0; iblk < 8; ++iblk) {
        const char* bbase = (const char*)lB16[iblk & 1];
        loadB(bbase, 0, 0, bfA);             // s=0 B batch (after barrier)
#pragma unroll
        for (int s = 0; s < 6; ++s) {
            const int kk = s >> 1, ks = s & 1;
            // ---- issue next-subphase loads (ping-pong target) ----
            if (s < 5) {
                const int nk = (s + 1) >> 1, nz = (s + 1) & 1;
                if ((s + 1) & 1) { loadA(iblk, nk, nz, afB); loadB(bbase, nk, nz, bfB); }
                else             { loadA(iblk, nk, nz, afA); loadB(bbase, nk, nz, bfA); }
            } else if (iblk < 7) {
                loadA(iblk + 1, 0, 0, afA);  // next iblk's s=0 A (no barrier dep)
            }
            if (s == 0 && iblk < 7) stageB(iblk + 1, (iblk & 1) ^ 1);
            // ---- MFMA on current buffers ----
            const half8* afc = (s & 1) ? afB : afA;
            const half8* bfc = (s & 1) ? bfB : bfA;
#pragma unroll
            for (int mi = 0; mi < 4; ++mi)
#pragma unroll
                for (int ni = 0; ni < 4; ++ni)
                    acc[mi][ni] = __builtin_amdgcn_mfma_f32_16x16x32_f16(
                        afc[mi], bfc[ni], acc[mi][ni], 0, 0, 0);
        }
        __syncthreads();
    }

    // ---- epilogue ----
    const int mat = mblk >> 2;                         // 0=q 1=k 2=v
    const float* bias = (mat == 0) ? bq : (mat == 1) ? bk : bv;
    const int oBase = ((mblk & 3) << 7) + wm * 64 + kgrp * 4;
#pragma unroll
    for (int mi = 0; mi < 4; ++mi) {
#pragma unroll
        for (int r = 0; r < 4; ++r) {
            const int o = oBase + mi * 16 + r;         // channel within matrix
            const float bsv = bias[o];
            float vals[4];
            float mx = -3.0e38f;
#pragma unroll
            for (int ni = 0; ni < 4; ++ni) {
                float v = acc[mi][ni][r] + bsv;
                vals[ni] = v;
                mx = fmaxf(mx, v);
            }
#pragma unroll
            for (int d = 1; d < 16; d <<= 1) mx = fmaxf(mx, __shfl_xor(mx, d, 64));
            if (mat == 0) {
                if (lane15 == 0) atomicMax(&qmaxU[bb * U_ + o], fmap(mx));
            } else {
                __half* buf = (mat == 1) ? kbuf : vbuf;
                size_t rowbase = ((size_t)bb * U_ + o) * L_ + l0 + wn * 64;
#pragma unroll
                for (int ni = 0; ni < 4; ++ni)
                    buf[rowbase + ni * 16 + lane15] = __float2half(vals[ni]);
                unsigned* mptr = (mat == 1) ? kmaxU : vmaxU;
                if (lane15 == 0) atomicMax(&mptr[bb * U_ + o], fmap(mx));
            }
        }
    }
}

// ---------------------------------------------------------------------------
// Kernel 3: per-(b,h) attention, 1024 threads. k-pass: one aligned dword load
// + 2 shfl per thread-iter (edges scalar only at wave boundaries).
// v-pass: lb = it*128 + ch*8 -> contiguous 256B per o-group (coalesced V) and
// pl[] bank conflict cut from 16-way to 4-way.
// ---------------------------------------------------------------------------
__global__ void __launch_bounds__(1024) attn_kernel(
    const __half* __restrict__ kbuf, const __half* __restrict__ vbuf,
    const unsigned* __restrict__ qmaxU, const unsigned* __restrict__ kmaxU,
    const unsigned* __restrict__ vmaxU,
    const int* __restrict__ g_mask, const int* __restrict__ t_mask,
    float* __restrict__ attout) {
    const int bh = blockIdx.x;
    const int b = bh >> 3, h = bh & 7;
    const int tid = threadIdx.x;
    const int lane = tid & 63;
    __shared__ float qs[64], kg[64], vg[64];
    __shared__ float pl[2048];
    __shared__ float red[1024];
    if (tid < 64) {
        qs[tid] = funmap(qmaxU[b * U_ + h * 64 + tid]);
        kg[tid] = funmap(kmaxU[b * U_ + h * 64 + tid]);
        vg[tid] = funmap(vmaxU[b * U_ + h * 64 + tid]);
    }
    __syncthreads();
    const float scale = 0.044194173824159216f;   // 1/sqrt(512)

    // logits for 2048 local (pooled) keys; thread owns 2 positions
    const __half* kbase = kbuf + ((size_t)b * U_ + h * 64) * L_;
    const int l0 = tid * 2;
    float acc0 = 0.f, acc1 = 0.f;
    for (int o = 0; o < 64; ++o) {
        const __half* row = kbase + (size_t)o * L_;
        const __half2 hv = *(const __half2*)(row + l0);
        float f1 = __half2float(hv.x), f2 = __half2float(hv.y);
        float fL = __shfl_up(f2, 1, 64);
        float fR = __shfl_down(f1, 1, 64);
        if (lane == 0)  fL = (l0 == 0) ? -3.0e38f : __half2float(row[l0 - 1]);
        if (lane == 63) fR = (l0 + 2 >= L_) ? -3.0e38f : __half2float(row[l0 + 2]);
        const float qw = qs[o];
        acc0 += qw * fmaxf(fL, fmaxf(f1, f2));
        acc1 += qw * fmaxf(f1, fmaxf(f2, fR));
    }
    float lmax = -3.0e38f;
    {
        int tm0 = t_mask[b * L_ + l0], tm1 = t_mask[b * L_ + l0 + 1];
        float lg0 = (tm0 == 0) ? -INFINITY : acc0 * scale;
        float lg1 = (tm1 == 0) ? -INFINITY : acc1 * scale;
        pl[l0] = lg0; pl[l0 + 1] = lg1;
        lmax = fmaxf(lg0, lg1);
    }
    // global-key logit (redundantly on all threads; cheap)
    float ag = 0.f;
    for (int d = 0; d < 64; ++d) ag += qs[d] * kg[d];
    const int gm = g_mask[b];
    float lgg = gm ? ag * scale : -INFINITY;
    // block max
    red[tid] = lmax; __syncthreads();
    for (int s = 512; s > 0; s >>= 1) {
        if (tid < s) red[tid] = fmaxf(red[tid], red[tid + s]);
        __syncthreads();
    }
    float mx = fmaxf(red[0], lgg);
    __syncthreads();
    // exponentials + denominator
    {
        float lg0 = pl[l0], lg1 = pl[l0 + 1];
        float e0 = (lg0 <= -3.0e38f) ? 0.f : __expf(lg0 - mx);
        float e1 = (lg1 <= -3.0e38f) ? 0.f : __expf(lg1 - mx);
        pl[l0] = e0; pl[l0 + 1] = e1;
        red[tid] = e0 + e1;
    }
    __syncthreads();
    for (int s = 512; s > 0; s >>= 1) {
        if (tid < s) red[tid] += red[tid + s];
        __syncthreads();
    }
    float eg = gm ? __expf(lgg - mx) : 0.f;
    float den = red[0] + eg;
    if (!(den > 0.f)) den = 1.f;
    __syncthreads();
    // weighted sum of pooled values: thread = (o = tid/16, 16 interleaved 8-chunks)
    const int o = tid >> 4;
    const int ch = tid & 15;
    const __half* vrow = vbuf + ((size_t)b * U_ + h * 64 + o) * L_;
    float s = 0.f;
    for (int it = 0; it < 16; ++it) {
        const int lb = it * 128 + ch * 8;
        union { uint4 u; __half hh[8]; } pk;
        pk.u = *(const uint4*)(vrow + lb);
        float f[10];
#pragma unroll
        for (int j = 0; j < 8; ++j) f[j + 1] = __half2float(pk.hh[j]);
        f[0] = (lb == 0) ? -3.0e38f : __half2float(vrow[lb - 1]);
        f[9] = (lb + 8 >= L_) ? -3.0e38f : __half2float(vrow[lb + 8]);
#pragma unroll
        for (int j = 0; j < 8; ++j)
            s += pl[lb + j] * fmaxf(f[j], fmaxf(f[j + 1], f[j + 2]));
    }
    red[tid] = s; __syncthreads();
    if (ch == 0) {
        float tot = 0.f;
#pragma unroll
        for (int q2 = 0; q2 < 16; ++q2) tot += red[(o << 4) + q2];
        float val = (eg * vg[o] + tot) / den;
        val *= (float)gm;
        attout[(size_t)b * U_ + h * 64 + o] = val;
    }
}

// ---------------------------------------------------------------------------
// Kernel 4: head mix (H x H) + output projection via WoT (coalesced)
// ---------------------------------------------------------------------------
__global__ void __launch_bounds__(512) out_kernel(
    const float* __restrict__ attout,
    const float* __restrict__ Wh, const float* __restrict__ bh,
    const float* __restrict__ WoT, const float* __restrict__ bo,
    float* __restrict__ out) {
    const int b = blockIdx.x;
    const int tid = threadIdx.x;
    __shared__ float tmp[512];
    const int oh = tid >> 6, d = tid & 63;
    float s = bh[oh];
#pragma unroll
    for (int i = 0; i < 8; ++i)
        s += Wh[oh * 8 + i] * attout[b * U_ + i * 64 + d];
    tmp[oh * 64 + d] = s;          // u = h*64 + d
    __syncthreads();
    float s2 = bo[tid];
    for (int i = 0; i < 512; ++i) s2 += WoT[i * 512 + tid] * tmp[i];
    out[b * U_ + tid] = s2;
}

// ---------------------------------------------------------------------------
extern "C" void kernel_launch(void* const* d_in, const int* in_sizes, int n_in,
                              void* d_out, int out_size, void* d_ws, size_t ws_size,
                              hipStream_t stream) {
    const float* t  = (const float*)d_in[0];
    // d_in[1] = g : unused by the reference
    const int* g_mask = (const int*)d_in[2];
    const int* t_mask = (const int*)d_in[3];
    const float* Wq = (const float*)d_in[4];
    const float* bq = (const float*)d_in[5];
    const float* Wk = (const float*)d_in[6];
    const float* bk = (const float*)d_in[7];
    const float* Wv = (const float*)d_in[8];
    const float* bv = (const float*)d_in[9];
    const float* Wh = (const float*)d_in[10];
    const float* bh = (const float*)d_in[11];
    const float* Wo = (const float*)d_in[12];
    const float* bo = (const float*)d_in[13];

    char* ws = (char*)d_ws;
    __half* Wrp2 = (__half*)ws;                                      // 4,718,592 B
    float* WoT   = (float*)(ws + 4718592);                           // 1,048,576 B
    __half* t16  = (__half*)(ws + 5767168);                          // 67,108,864 B
    __half* kbuf = (__half*)(ws + 5767168 + 67108864);               // 67,108,864 B
    __half* vbuf = (__half*)(ws + 5767168 + 2 * 67108864);           // 67,108,864 B
    unsigned* qmaxU = (unsigned*)(ws + 5767168 + 3 * 67108864);
    unsigned* kmaxU = qmaxU + 16384;
    unsigned* vmaxU = kmaxU + 16384;
    float* attout = (float*)(vmaxU + 16384);

    (void)hipMemsetAsync(qmaxU, 0, 3 * 16384 * sizeof(unsigned), stream);
    t_cvt<<<16384, 256, 0, stream>>>(t, t16);
    repack_w2<<<1152, 256, 0, stream>>>(Wq, Wk, Wv, Wrp2);
    wot_repack<<<1024, 256, 0, stream>>>(Wo, WoT);
    conv_gemm<<<6144, 256, 0, stream>>>(t16, Wrp2, bq, bk, bv, kbuf, vbuf,
                                        qmaxU, kmaxU, vmaxU);
    attn_kernel<<<256, 1024, 0, stream>>>(kbuf, vbuf, qmaxU, kmaxU, vmaxU,
                                          g_mask, t_mask, attout);
    out_kernel<<<32, 512, 0, stream>>>(attout, Wh, bh, WoT, bo, (float*)d_out);
}